// Round 6
// baseline (73.438 us; speedup 1.0000x reference)
//
#include <hip/hip_runtime.h>
#include <cstddef>

constexpr int NGF    = 80;
constexpr int TLEN   = 1000;
constexpr int SPLICE = 10;
constexpr int PATCH  = 2 * SPLICE + 1;  // 21
constexpr int NH     = 50;
constexpr int TC     = 20;              // t per block (divides 1000 exactly)
constexpr int SW     = TC + 31;         // 51: c = tt + k reaches tt+31 (k-slot pad)
constexpr float NL2E = -1.44269504088896341f;

typedef __attribute__((ext_vector_type(8))) short  short8;
typedef __attribute__((ext_vector_type(4))) float  f32x4;

__device__ __forceinline__ unsigned short f32_to_bf16(float f) {
    unsigned int u = __builtin_bit_cast(unsigned int, f);
    u += 0x7fffu + ((u >> 16) & 1u);   // RNE
    return (unsigned short)(u >> 16);
}

#define SIG(s) __builtin_amdgcn_rcpf(1.0f + __builtin_amdgcn_exp2f(s))

__global__ __launch_bounds__(256) void relevance_mfma(
    const float* __restrict__ x,    // [B, NGF, TLEN]
    const float* __restrict__ W1,   // [NH, PATCH]
    const float* __restrict__ b1,   // [NH]
    const float* __restrict__ W2,   // [NH]
    const float* __restrict__ b2,   // [1]
    float* __restrict__ out)        // [B, TLEN, NGF]
{
    const int tid  = threadIdx.x;
    const int wave = tid >> 6;
    const int lane = tid & 63;
    const int q    = lane >> 4;
    const int jj   = lane & 15;
    const int t0   = blockIdx.x * TC;
    const int b    = blockIdx.y;

    __shared__ float seg[NGF * SW];     // seg[f][c] = xpad[b][f][t0+c]

    // ---- stage x region (zero-padded); finite garbage beyond patch is fine
    const float* xb = x + (size_t)b * NGF * TLEN;
    for (int i = tid; i < NGF * SW; i += 256) {
        const unsigned f = (unsigned)i / SW;
        const int c = i - (int)f * SW;
        const int gx = t0 + c - SPLICE;
        seg[i] = (gx >= 0 && gx < TLEN) ? xb[f * TLEN + gx] : 0.0f;
    }

    // ---- A fragments = W1 (M = j), loop-invariant. A[m=jj][k=8q+e].
    // Pre-scaled by -log2(e); bias b1 folded into spare k-slot 21.
    union FragU { unsigned short us[8]; short8 s8; int i32[4]; };
    FragU w1f0, w1f1, w1f2, w1f3;
#define BUILD_A(N, DST)                                                     \
    {                                                                       \
        const int j = 16 * N + jj;                                          \
        _Pragma("unroll")                                                   \
        for (int e = 0; e < 8; ++e) {                                       \
            const int k = 8 * q + e;                                        \
            float v = 0.0f;                                                 \
            if (j < NH) {                                                   \
                if (k < PATCH)       v = NL2E * W1[j * PATCH + k];          \
                else if (k == PATCH) v = NL2E * b1[j];                      \
            }                                                               \
            DST.us[e] = f32_to_bf16(v);                                     \
        }                                                                   \
    }
    BUILD_A(0, w1f0) BUILD_A(1, w1f1) BUILD_A(2, w1f2) BUILD_A(3, w1f3)
#undef BUILD_A

    // per-lane W2 (scaled by -log2e): lane (q,jj) owns j = 16n + 4q + r
    float w2v[16];
    #pragma unroll
    for (int n = 0; n < 4; ++n)
        #pragma unroll
        for (int r = 0; r < 4; ++r) {
            const int j = 16 * n + 4 * q + r;
            w2v[4 * n + r] = (j < NH) ? NL2E * W2[j] : 0.0f;
        }
    const float nb2 = NL2E * b2[0];

    __syncthreads();

    // ---- tiles: tile = (tt, fc); M=64 j, N=16 f, one t per tile
    for (int tile = wave; tile < 5 * TC; tile += 4) {
        const unsigned ut = (unsigned)tile;
        const int tt = ut / 5u;
        const int fc = (int)ut - 5 * tt;
        const int f0 = fc * 16;

        // B[c=jj][k=8q+e] = seg[f0+jj][tt + 8q + e]
        const float* sp = &seg[(f0 + jj) * SW + tt + 8 * q];
        const float p0 = sp[0], p1 = sp[1], p2 = sp[2], p3 = sp[3];
        const float p4 = sp[4], p5 = sp[5], p6 = sp[6], p7 = sp[7];

        int a0, a1, a2, a3;
        asm("v_cvt_pk_bf16_f32 %0, %1, %2" : "=v"(a0) : "v"(p0), "v"(p1));
        asm("v_cvt_pk_bf16_f32 %0, %1, %2" : "=v"(a1) : "v"(p2), "v"(p3));
        asm("v_cvt_pk_bf16_f32 %0, %1, %2" : "=v"(a2) : "v"(p4), "v"(p5));
        asm("v_cvt_pk_bf16_f32 %0, %1, %2" : "=v"(a3) : "v"(p6), "v"(p7));
        union { int i[4]; short8 s8; } bf;
        // k=21 slot (q==2, element 5 = high half of dword 2) must be 1.0
        // so A's b1 column contributes the bias; k=22..31 meet zeros in A.
        bf.i[0] = a0; bf.i[1] = a1;
        bf.i[2] = (q == 2) ? ((a2 & 0x0000FFFF) | 0x3F800000) : a2;
        bf.i[3] = a3;

        f32x4 acc0 = {0,0,0,0}, acc1 = {0,0,0,0}, acc2 = {0,0,0,0}, acc3 = {0,0,0,0};
        acc0 = __builtin_amdgcn_mfma_f32_16x16x32_bf16(w1f0.s8, bf.s8, acc0, 0, 0, 0);
        acc1 = __builtin_amdgcn_mfma_f32_16x16x32_bf16(w1f1.s8, bf.s8, acc1, 0, 0, 0);
        acc2 = __builtin_amdgcn_mfma_f32_16x16x32_bf16(w1f2.s8, bf.s8, acc2, 0, 0, 0);
        acc3 = __builtin_amdgcn_mfma_f32_16x16x32_bf16(w1f3.s8, bf.s8, acc3, 0, 0, 0);
        // lane (q,jj): acc{n}[r] = -log2e*(W1·patch + b1) for j=16n+4q+r, f=f0+jj

        float zp0 = 0.f, zp1 = 0.f, zp2 = 0.f, zp3 = 0.f;
#define EPI(ACC, N, ZP)                                  \
        ZP = fmaf(w2v[4*N+0], SIG(ACC[0]), ZP);          \
        ZP = fmaf(w2v[4*N+1], SIG(ACC[1]), ZP);          \
        ZP = fmaf(w2v[4*N+2], SIG(ACC[2]), ZP);          \
        ZP = fmaf(w2v[4*N+3], SIG(ACC[3]), ZP);
        EPI(acc0, 0, zp0) EPI(acc1, 1, zp1) EPI(acc2, 2, zp2) EPI(acc3, 3, zp3)
#undef EPI
        float z = (zp0 + zp1) + (zp2 + zp3);

        z += __shfl_xor(z, 16);      // reduce across q (j-partials)
        z += __shfl_xor(z, 32);
        const float o = SIG(z + nb2);

        if (lane < 16)               // 16 lanes -> one aligned 64B line
            out[((size_t)b * TLEN + t0 + tt) * NGF + f0 + lane] = o;
    }
}

extern "C" void kernel_launch(void* const* d_in, const int* in_sizes, int n_in,
                              void* d_out, int out_size, void* d_ws, size_t ws_size,
                              hipStream_t stream) {
    const float* x  = (const float*)d_in[0];
    const float* W1 = (const float*)d_in[1];
    const float* b1 = (const float*)d_in[2];
    const float* W2 = (const float*)d_in[3];
    const float* b2 = (const float*)d_in[4];
    float* out = (float*)d_out;

    const int B = in_sizes[0] / (NGF * TLEN);  // 32

    dim3 grid(TLEN / TC, B);                   // (50, 32) = 1600 blocks
    relevance_mfma<<<grid, 256, 0, stream>>>(x, W1, b1, W2, b2, out);
}

// Round 7
// 67.999 us; speedup vs baseline: 1.0800x; 1.0800x over previous
//
#include <hip/hip_runtime.h>
#include <cstddef>

constexpr int NGF    = 80;
constexpr int TLEN   = 1000;
constexpr int SPLICE = 10;
constexpr int PATCH  = 2 * SPLICE + 1;  // 21
constexpr int NH     = 50;
constexpr int FB     = 16;              // f per block
constexpr int TC     = 40;              // t per block (25 chunks x 5 f-chunks)
constexpr int SW     = TC + 31;         // 71: c = tt + k reaches tt+31 (k-slot pad)
constexpr float NL2E = -1.44269504088896341f;

typedef __attribute__((ext_vector_type(8))) short  short8;
typedef __attribute__((ext_vector_type(4))) float  f32x4;

__device__ __forceinline__ unsigned short f32_to_bf16(float f) {
    unsigned int u = __builtin_bit_cast(unsigned int, f);
    u += 0x7fffu + ((u >> 16) & 1u);   // RNE
    return (unsigned short)(u >> 16);
}

#define SIG(s) __builtin_amdgcn_rcpf(1.0f + __builtin_amdgcn_exp2f(s))

__global__ __launch_bounds__(256) void relevance_mfma(
    const float* __restrict__ x,    // [B, NGF, TLEN]
    const float* __restrict__ W1,   // [NH, PATCH]
    const float* __restrict__ b1,   // [NH]
    const float* __restrict__ W2,   // [NH]
    const float* __restrict__ b2,   // [1]
    float* __restrict__ out)        // [B, TLEN, NGF]
{
    const int tid  = threadIdx.x;
    const int wave = tid >> 6;
    const int lane = tid & 63;
    const int q    = lane >> 4;
    const int jj   = lane & 15;
    const unsigned bx = blockIdx.x;
    const int fc   = bx % 5u;           // f-chunk
    const int tc   = bx / 5u;           // t-chunk
    const int f0   = fc * FB;
    const int t0   = tc * TC;
    const int b    = blockIdx.y;

    __shared__ float seg[FB * SW];      // seg[fl][c] = xpad[b][f0+fl][t0+c]

    // ---- stage x region (zero-padded). 16 rows x 71 floats = 1136 elems.
    const float* xb = x + ((size_t)b * NGF + f0) * TLEN;
    for (int i = tid; i < FB * SW; i += 256) {
        const unsigned fl = (unsigned)i / SW;
        const int c = i - (int)fl * SW;
        const int gx = t0 + c - SPLICE;
        seg[i] = (gx >= 0 && gx < TLEN) ? xb[fl * TLEN + gx] : 0.0f;
    }

    // ---- A fragments = W1 (M = j), loop-invariant. A[m=jj][k=8q+e].
    // Pre-scaled by -log2(e); bias b1 folded into spare k-slot 21.
    union FragU { unsigned short us[8]; short8 s8; };
    FragU w1f0, w1f1, w1f2, w1f3;
#define BUILD_A(N, DST)                                                     \
    {                                                                       \
        const int j = 16 * N + jj;                                          \
        _Pragma("unroll")                                                   \
        for (int e = 0; e < 8; ++e) {                                       \
            const int k = 8 * q + e;                                        \
            float v = 0.0f;                                                 \
            if (j < NH) {                                                   \
                if (k < PATCH)       v = NL2E * W1[j * PATCH + k];          \
                else if (k == PATCH) v = NL2E * b1[j];                      \
            }                                                               \
            DST.us[e] = f32_to_bf16(v);                                     \
        }                                                                   \
    }
    BUILD_A(0, w1f0) BUILD_A(1, w1f1) BUILD_A(2, w1f2) BUILD_A(3, w1f3)
#undef BUILD_A

    // per-lane W2 (scaled by -log2e): lane (q,jj) owns j = 16n + 4q + r
    float w2v[16];
    #pragma unroll
    for (int n = 0; n < 4; ++n)
        #pragma unroll
        for (int r = 0; r < 4; ++r) {
            const int j = 16 * n + 4 * q + r;
            w2v[4 * n + r] = (j < NH) ? NL2E * W2[j] : 0.0f;
        }
    const float nb2 = NL2E * b2[0];

    __syncthreads();

    // ---- tiles: one t per tile; M=64 j, N=16 f. 10 tiles per wave.
    for (int tt = wave; tt < TC; tt += 4) {
        // B[c=jj][k=8q+e] = seg[jj][tt + 8q + e]; stride 71 -> free 2-way banks
        const float* sp = &seg[jj * SW + tt + 8 * q];
        const float p0 = sp[0], p1 = sp[1], p2 = sp[2], p3 = sp[3];
        const float p4 = sp[4], p5 = sp[5], p6 = sp[6], p7 = sp[7];

        int a0, a1, a2, a3;
        asm("v_cvt_pk_bf16_f32 %0, %1, %2" : "=v"(a0) : "v"(p0), "v"(p1));
        asm("v_cvt_pk_bf16_f32 %0, %1, %2" : "=v"(a1) : "v"(p2), "v"(p3));
        asm("v_cvt_pk_bf16_f32 %0, %1, %2" : "=v"(a2) : "v"(p4), "v"(p5));
        asm("v_cvt_pk_bf16_f32 %0, %1, %2" : "=v"(a3) : "v"(p6), "v"(p7));
        union { int i[4]; short8 s8; } bf;
        // k=21 slot (q==2, hi half of dword 2) := 1.0 so A's b1 column fires.
        bf.i[0] = a0; bf.i[1] = a1;
        bf.i[2] = (q == 2) ? ((a2 & 0x0000FFFF) | 0x3F800000) : a2;
        bf.i[3] = a3;

        f32x4 acc0 = {0,0,0,0}, acc1 = {0,0,0,0}, acc2 = {0,0,0,0}, acc3 = {0,0,0,0};
        acc0 = __builtin_amdgcn_mfma_f32_16x16x32_bf16(w1f0.s8, bf.s8, acc0, 0, 0, 0);
        acc1 = __builtin_amdgcn_mfma_f32_16x16x32_bf16(w1f1.s8, bf.s8, acc1, 0, 0, 0);
        acc2 = __builtin_amdgcn_mfma_f32_16x16x32_bf16(w1f2.s8, bf.s8, acc2, 0, 0, 0);
        acc3 = __builtin_amdgcn_mfma_f32_16x16x32_bf16(w1f3.s8, bf.s8, acc3, 0, 0, 0);
        // lane (q,jj): acc{n}[r] = -log2e*(W1·patch + b1) for j=16n+4q+r, f=f0+jj

        float zp0 = 0.f, zp1 = 0.f, zp2 = 0.f, zp3 = 0.f;
#define EPI(ACC, N, ZP)                                  \
        ZP = fmaf(w2v[4*N+0], SIG(ACC[0]), ZP);          \
        ZP = fmaf(w2v[4*N+1], SIG(ACC[1]), ZP);          \
        ZP = fmaf(w2v[4*N+2], SIG(ACC[2]), ZP);          \
        ZP = fmaf(w2v[4*N+3], SIG(ACC[3]), ZP);
        EPI(acc0, 0, zp0) EPI(acc1, 1, zp1) EPI(acc2, 2, zp2) EPI(acc3, 3, zp3)
#undef EPI
        float z = (zp0 + zp1) + (zp2 + zp3);

        z += __shfl_xor(z, 16);      // reduce across q (j-partials)
        z += __shfl_xor(z, 32);
        const float o = SIG(z + nb2);

        if (lane < 16)               // 16 lanes -> one aligned 64B line
            out[((size_t)b * TLEN + t0 + tt) * NGF + f0 + lane] = o;
    }
}

extern "C" void kernel_launch(void* const* d_in, const int* in_sizes, int n_in,
                              void* d_out, int out_size, void* d_ws, size_t ws_size,
                              hipStream_t stream) {
    const float* x  = (const float*)d_in[0];
    const float* W1 = (const float*)d_in[1];
    const float* b1 = (const float*)d_in[2];
    const float* W2 = (const float*)d_in[3];
    const float* b2 = (const float*)d_in[4];
    float* out = (float*)d_out;

    const int B = in_sizes[0] / (NGF * TLEN);  // 32

    dim3 grid((TLEN / TC) * 5, B);             // (125, 32) = 4000 blocks
    relevance_mfma<<<grid, 256, 0, stream>>>(x, W1, b1, W2, b2, out);
}

// Round 8
// 59.839 us; speedup vs baseline: 1.2273x; 1.1364x over previous
//
#include <hip/hip_runtime.h>
#include <cstddef>

constexpr int NGF    = 80;
constexpr int TLEN   = 1000;
constexpr int SPLICE = 10;
constexpr int PATCH  = 2 * SPLICE + 1;  // 21
constexpr int NH     = 50;
constexpr int FB     = 16;              // f per block
constexpr int TC     = 40;              // t per block
constexpr int SW     = TC + 31;         // 71: c = tt + k reaches tt+31 (k-slot pad)
constexpr float NL2E = -1.44269504088896341f;

typedef __attribute__((ext_vector_type(8))) short  short8;
typedef __attribute__((ext_vector_type(4))) float  f32x4;

__device__ __forceinline__ unsigned short f32_to_bf16(float f) {
    unsigned int u = __builtin_bit_cast(unsigned int, f);
    u += 0x7fffu + ((u >> 16) & 1u);   // RNE
    return (unsigned short)(u >> 16);
}

#define SIG(s) __builtin_amdgcn_rcpf(1.0f + __builtin_amdgcn_exp2f(s))

__global__ __launch_bounds__(256, 8) void relevance_mfma(
    const float* __restrict__ x,    // [B, NGF, TLEN]
    const float* __restrict__ W1,   // [NH, PATCH]
    const float* __restrict__ b1,   // [NH]
    const float* __restrict__ W2,   // [NH]
    const float* __restrict__ b2,   // [1]
    float* __restrict__ out)        // [B, TLEN, NGF]
{
    const int tid  = threadIdx.x;
    const int wave = tid >> 6;
    const int lane = tid & 63;
    const int q    = lane >> 4;
    const int jj   = lane & 15;
    const unsigned bx = blockIdx.x;
    const int fc   = bx % 5u;           // f-chunk
    const int tc   = bx / 5u;           // t-chunk
    const int f0   = fc * FB;
    const int t0   = tc * TC;
    const int b    = blockIdx.y;

    __shared__ float seg[FB * SW];      // seg[fl][c] = xpad[b][f0+fl][t0+c]

    const float* xb = x + ((size_t)b * NGF + f0) * TLEN;
    for (int i = tid; i < FB * SW; i += 256) {
        const unsigned fl = (unsigned)i / SW;
        const int c = i - (int)fl * SW;
        const int gx = t0 + c - SPLICE;
        seg[i] = (gx >= 0 && gx < TLEN) ? xb[fl * TLEN + gx] : 0.0f;
    }

    // ---- A fragments = W1 (M = j), loop-invariant. A[m=jj][k=8q+e].
    // Pre-scaled by -log2(e); bias b1 folded into spare k-slot 21.
    union FragU { unsigned short us[8]; short8 s8; };
    FragU w1f0, w1f1, w1f2, w1f3;
#define BUILD_A(N, DST)                                                     \
    {                                                                       \
        const int j = 16 * N + jj;                                          \
        _Pragma("unroll")                                                   \
        for (int e = 0; e < 8; ++e) {                                       \
            const int k = 8 * q + e;                                        \
            float v = 0.0f;                                                 \
            if (j < NH) {                                                   \
                if (k < PATCH)       v = NL2E * W1[j * PATCH + k];          \
                else if (k == PATCH) v = NL2E * b1[j];                      \
            }                                                               \
            DST.us[e] = f32_to_bf16(v);                                     \
        }                                                                   \
    }
    BUILD_A(0, w1f0) BUILD_A(1, w1f1) BUILD_A(2, w1f2) BUILD_A(3, w1f3)
#undef BUILD_A

    // per-lane W2 (scaled by -log2e): lane (q,jj) owns j = 16n + 4q + r
    float w2v[16];
    #pragma unroll
    for (int n = 0; n < 4; ++n)
        #pragma unroll
        for (int r = 0; r < 4; ++r) {
            const int j = 16 * n + 4 * q + r;
            w2v[4 * n + r] = (j < NH) ? NL2E * W2[j] : 0.0f;
        }
    const float nb2 = NL2E * b2[0];

    __syncthreads();

    // ---- tiles: one t per tile; M=64 j, N=16 f
    for (int tt = wave; tt < TC; tt += 4) {
        const float* sp = &seg[jj * SW + tt + 8 * q];
        const float p0 = sp[0], p1 = sp[1], p2 = sp[2], p3 = sp[3];
        const float p4 = sp[4], p5 = sp[5], p6 = sp[6], p7 = sp[7];

        int a0, a1, a2, a3;
        asm("v_cvt_pk_bf16_f32 %0, %1, %2" : "=v"(a0) : "v"(p0), "v"(p1));
        asm("v_cvt_pk_bf16_f32 %0, %1, %2" : "=v"(a1) : "v"(p2), "v"(p3));
        asm("v_cvt_pk_bf16_f32 %0, %1, %2" : "=v"(a2) : "v"(p4), "v"(p5));
        asm("v_cvt_pk_bf16_f32 %0, %1, %2" : "=v"(a3) : "v"(p6), "v"(p7));
        union { int i[4]; short8 s8; } bf;
        // k=21 slot (q==2, hi half of dword 2) := 1.0 so A's b1 column fires.
        bf.i[0] = a0; bf.i[1] = a1;
        bf.i[2] = (q == 2) ? ((a2 & 0x0000FFFF) | 0x3F800000) : a2;
        bf.i[3] = a3;

        f32x4 acc0 = {0,0,0,0}, acc1 = {0,0,0,0}, acc2 = {0,0,0,0}, acc3 = {0,0,0,0};
        acc0 = __builtin_amdgcn_mfma_f32_16x16x32_bf16(w1f0.s8, bf.s8, acc0, 0, 0, 0);
        acc1 = __builtin_amdgcn_mfma_f32_16x16x32_bf16(w1f1.s8, bf.s8, acc1, 0, 0, 0);
        acc2 = __builtin_amdgcn_mfma_f32_16x16x32_bf16(w1f2.s8, bf.s8, acc2, 0, 0, 0);
        acc3 = __builtin_amdgcn_mfma_f32_16x16x32_bf16(w1f3.s8, bf.s8, acc3, 0, 0, 0);
        // acc{n}[r] = -log2e*(W1·patch + b1) for j=16n+4q+r, f=f0+jj

        // ---- quad-rational epilogue: one rcp per 4 hidden units.
        // sum_i w_i/(1+u_i), u_i = exp2(acc_i):
        //   n01 = (w0+w1) + w0*u1 + w1*u0 ; d01 = 1 + (u0+u1) + u0*u1
        //   nq  = n01*d23 + n23*d01      ; dq  = d01*d23
        float z = 0.0f;
#define QUAD(ACC, N)                                                         \
        {                                                                    \
            const float w0 = w2v[4*N+0], w1 = w2v[4*N+1];                    \
            const float w2_ = w2v[4*N+2], w3 = w2v[4*N+3];                   \
            const float u0 = __builtin_amdgcn_exp2f(ACC[0]);                 \
            const float u1 = __builtin_amdgcn_exp2f(ACC[1]);                 \
            const float u2 = __builtin_amdgcn_exp2f(ACC[2]);                 \
            const float u3 = __builtin_amdgcn_exp2f(ACC[3]);                 \
            const float n01 = fmaf(w0, u1, fmaf(w1, u0, w0 + w1));           \
            const float n23 = fmaf(w2_, u3, fmaf(w3, u2, w2_ + w3));         \
            const float d01 = fmaf(u0, u1, u0 + u1) + 1.0f;                  \
            const float d23 = fmaf(u2, u3, u2 + u3) + 1.0f;                  \
            const float nq  = fmaf(n01, d23, n23 * d01);                     \
            const float dq  = d01 * d23;                                     \
            z = fmaf(nq, __builtin_amdgcn_rcpf(dq), z);                      \
        }
        QUAD(acc0, 0) QUAD(acc1, 1) QUAD(acc2, 2) QUAD(acc3, 3)
#undef QUAD

        z += __shfl_xor(z, 16);      // reduce across q (j-partials)
        z += __shfl_xor(z, 32);
        const float o = SIG(z + nb2);

        if (lane < 16)               // 16 lanes -> one aligned 64B line
            out[((size_t)b * TLEN + t0 + tt) * NGF + f0 + lane] = o;
    }
}

extern "C" void kernel_launch(void* const* d_in, const int* in_sizes, int n_in,
                              void* d_out, int out_size, void* d_ws, size_t ws_size,
                              hipStream_t stream) {
    const float* x  = (const float*)d_in[0];
    const float* W1 = (const float*)d_in[1];
    const float* b1 = (const float*)d_in[2];
    const float* W2 = (const float*)d_in[3];
    const float* b2 = (const float*)d_in[4];
    float* out = (float*)d_out;

    const int B = in_sizes[0] / (NGF * TLEN);  // 32

    dim3 grid((TLEN / TC) * 5, B);             // (125, 32) = 4000 blocks
    relevance_mfma<<<grid, 256, 0, stream>>>(x, W1, b1, W2, b2, out);
}

// Round 9
// 58.506 us; speedup vs baseline: 1.2552x; 1.0228x over previous
//
#include <hip/hip_runtime.h>
#include <cstddef>

constexpr int NGF    = 80;
constexpr int TLEN   = 1000;
constexpr int SPLICE = 10;
constexpr int PATCH  = 2 * SPLICE + 1;  // 21
constexpr int NH     = 50;
constexpr int FB     = 16;              // f per block
constexpr int TC     = 40;              // t per block
constexpr int SW     = 74;              // even (float2 loads); 74%32 spreads banks
constexpr float NL2E = -1.44269504088896341f;

typedef __attribute__((ext_vector_type(8))) short  short8;
typedef __attribute__((ext_vector_type(4))) float  f32x4;

__device__ __forceinline__ unsigned short f32_to_bf16(float f) {
    unsigned int u = __builtin_bit_cast(unsigned int, f);
    u += 0x7fffu + ((u >> 16) & 1u);   // RNE
    return (unsigned short)(u >> 16);
}

#define SIG(s) __builtin_amdgcn_rcpf(1.0f + __builtin_amdgcn_exp2f(s))

__global__ __launch_bounds__(256, 4) void relevance_mfma(
    const float* __restrict__ x,    // [B, NGF, TLEN]
    const float* __restrict__ W1,   // [NH, PATCH]
    const float* __restrict__ b1,   // [NH]
    const float* __restrict__ W2,   // [NH]
    const float* __restrict__ b2,   // [1]
    float* __restrict__ out)        // [B, TLEN, NGF]
{
    const int tid  = threadIdx.x;
    const int wave = tid >> 6;
    const int lane = tid & 63;
    const int q    = lane >> 4;
    const int jj   = lane & 15;
    const unsigned bx = blockIdx.x;
    const int fc   = bx % 5u;           // f-chunk
    const int tc   = bx / 5u;           // t-chunk
    const int f0   = fc * FB;
    const int t0   = tc * TC;
    const int b    = blockIdx.y;

    __shared__ float seg[FB * SW];      // seg[fl][c] = xpad[b][f0+fl][t0+c]

    const float* xb = x + ((size_t)b * NGF + f0) * TLEN;
    for (int i = tid; i < FB * SW; i += 256) {
        const unsigned fl = (unsigned)i / SW;
        const int c = i - (int)fl * SW;
        const int gx = t0 + c - SPLICE;
        seg[i] = (gx >= 0 && gx < TLEN) ? xb[fl * TLEN + gx] : 0.0f;
    }

    // ---- A fragments = W1 (M = j), loop-invariant. A[m=jj][k=8q+e].
    // Pre-scaled by -log2(e); bias b1 folded into spare k-slot 21.
    union FragU { unsigned short us[8]; short8 s8; };
    FragU w1f0, w1f1, w1f2, w1f3;
#define BUILD_A(N, DST)                                                     \
    {                                                                       \
        const int j = 16 * N + jj;                                          \
        _Pragma("unroll")                                                   \
        for (int e = 0; e < 8; ++e) {                                       \
            const int k = 8 * q + e;                                        \
            float v = 0.0f;                                                 \
            if (j < NH) {                                                   \
                if (k < PATCH)       v = NL2E * W1[j * PATCH + k];          \
                else if (k == PATCH) v = NL2E * b1[j];                      \
            }                                                               \
            DST.us[e] = f32_to_bf16(v);                                     \
        }                                                                   \
    }
    BUILD_A(0, w1f0) BUILD_A(1, w1f1) BUILD_A(2, w1f2) BUILD_A(3, w1f3)
#undef BUILD_A

    // per-lane W2 (scaled by -log2e): lane (q,jj) owns j = 16n + 4q + r
    float w2v[16];
    #pragma unroll
    for (int n = 0; n < 4; ++n)
        #pragma unroll
        for (int r = 0; r < 4; ++r) {
            const int j = 16 * n + 4 * q + r;
            w2v[4 * n + r] = (j < NH) ? NL2E * W2[j] : 0.0f;
        }
    const float nb2 = NL2E * b2[0];

    __syncthreads();

    // quad-rational: one rcp per 4 hidden units (exact algebra, fp32-safe:
    // u <= 2^9 -> d_quad <= 7e10).  PAIR: acc3 has only j=48,49 live.
#define QUAD(ACC, N, Z)                                                      \
        {                                                                    \
            const float w0 = w2v[4*N+0], w1 = w2v[4*N+1];                    \
            const float w2_ = w2v[4*N+2], w3 = w2v[4*N+3];                   \
            const float u0 = __builtin_amdgcn_exp2f(ACC[0]);                 \
            const float u1 = __builtin_amdgcn_exp2f(ACC[1]);                 \
            const float u2 = __builtin_amdgcn_exp2f(ACC[2]);                 \
            const float u3 = __builtin_amdgcn_exp2f(ACC[3]);                 \
            const float n01 = fmaf(w0, u1, fmaf(w1, u0, w0 + w1));           \
            const float n23 = fmaf(w2_, u3, fmaf(w3, u2, w2_ + w3));         \
            const float d01 = fmaf(u0, u1, u0 + u1) + 1.0f;                  \
            const float d23 = fmaf(u2, u3, u2 + u3) + 1.0f;                  \
            const float nq  = fmaf(n01, d23, n23 * d01);                     \
            const float dq  = d01 * d23;                                     \
            Z = fmaf(nq, __builtin_amdgcn_rcpf(dq), Z);                      \
        }
#define PAIR(ACC, Z)                                                         \
        {                                                                    \
            const float w0 = w2v[12], w1 = w2v[13];                          \
            const float u0 = __builtin_amdgcn_exp2f(ACC[0]);                 \
            const float u1 = __builtin_amdgcn_exp2f(ACC[1]);                 \
            const float n01 = fmaf(w0, u1, fmaf(w1, u0, w0 + w1));           \
            const float d01 = fmaf(u0, u1, u0 + u1) + 1.0f;                  \
            Z = fmaf(n01, __builtin_amdgcn_rcpf(d01), Z);                    \
        }

    // ---- 2-tile iterations: tt0 even, tt1 = tt0+1; windows share 7/8 floats
    #pragma unroll
    for (int i = 0; i < 5; ++i) {
        const int tt0 = 2 * wave + 8 * i;
        const int tt1 = tt0 + 1;

        // 9 floats once: 4x float2 (even index) + 1
        const float2* sp2 = (const float2*)&seg[jj * SW + tt0 + 8 * q];
        const float2 q0 = sp2[0], q1 = sp2[1], q2 = sp2[2], q3 = sp2[3];
        const float p8 = ((const float*)(sp2 + 4))[0];
        const float p0 = q0.x, p1 = q0.y, p2 = q1.x, p3 = q1.y;
        const float p4 = q2.x, p5 = q2.y, p6 = q3.x, p7 = q3.y;

        int a0, a1, a2, a3, c0, c1, c2, c3;
        asm("v_cvt_pk_bf16_f32 %0, %1, %2" : "=v"(a0) : "v"(p0), "v"(p1));
        asm("v_cvt_pk_bf16_f32 %0, %1, %2" : "=v"(a1) : "v"(p2), "v"(p3));
        asm("v_cvt_pk_bf16_f32 %0, %1, %2" : "=v"(a2) : "v"(p4), "v"(p5));
        asm("v_cvt_pk_bf16_f32 %0, %1, %2" : "=v"(a3) : "v"(p6), "v"(p7));
        asm("v_cvt_pk_bf16_f32 %0, %1, %2" : "=v"(c0) : "v"(p1), "v"(p2));
        asm("v_cvt_pk_bf16_f32 %0, %1, %2" : "=v"(c1) : "v"(p3), "v"(p4));
        asm("v_cvt_pk_bf16_f32 %0, %1, %2" : "=v"(c2) : "v"(p5), "v"(p6));
        asm("v_cvt_pk_bf16_f32 %0, %1, %2" : "=v"(c3) : "v"(p7), "v"(p8));

        union { int i4[4]; short8 s8; } bfa, bfb;
        // k=21 slot (q==2, hi half of dword 2) := 1.0 so A's b1 column fires
        bfa.i4[0] = a0; bfa.i4[1] = a1;
        bfa.i4[2] = (q == 2) ? ((a2 & 0x0000FFFF) | 0x3F800000) : a2;
        bfa.i4[3] = a3;
        bfb.i4[0] = c0; bfb.i4[1] = c1;
        bfb.i4[2] = (q == 2) ? ((c2 & 0x0000FFFF) | 0x3F800000) : c2;
        bfb.i4[3] = c3;

        f32x4 s00 = {0,0,0,0}, s01 = {0,0,0,0}, s02 = {0,0,0,0}, s03 = {0,0,0,0};
        f32x4 s10 = {0,0,0,0}, s11 = {0,0,0,0}, s12 = {0,0,0,0}, s13 = {0,0,0,0};
        s00 = __builtin_amdgcn_mfma_f32_16x16x32_bf16(w1f0.s8, bfa.s8, s00, 0, 0, 0);
        s10 = __builtin_amdgcn_mfma_f32_16x16x32_bf16(w1f0.s8, bfb.s8, s10, 0, 0, 0);
        s01 = __builtin_amdgcn_mfma_f32_16x16x32_bf16(w1f1.s8, bfa.s8, s01, 0, 0, 0);
        s11 = __builtin_amdgcn_mfma_f32_16x16x32_bf16(w1f1.s8, bfb.s8, s11, 0, 0, 0);
        s02 = __builtin_amdgcn_mfma_f32_16x16x32_bf16(w1f2.s8, bfa.s8, s02, 0, 0, 0);
        s12 = __builtin_amdgcn_mfma_f32_16x16x32_bf16(w1f2.s8, bfb.s8, s12, 0, 0, 0);
        s03 = __builtin_amdgcn_mfma_f32_16x16x32_bf16(w1f3.s8, bfa.s8, s03, 0, 0, 0);
        s13 = __builtin_amdgcn_mfma_f32_16x16x32_bf16(w1f3.s8, bfb.s8, s13, 0, 0, 0);

        float z0 = 0.0f, z1 = 0.0f;
        QUAD(s00, 0, z0) QUAD(s10, 0, z1)
        QUAD(s01, 1, z0) QUAD(s11, 1, z1)
        QUAD(s02, 2, z0) QUAD(s12, 2, z1)
        PAIR(s03, z0)    PAIR(s13, z1)

        z0 += __shfl_xor(z0, 16);
        z0 += __shfl_xor(z0, 32);
        z1 += __shfl_xor(z1, 16);
        z1 += __shfl_xor(z1, 32);

        // lanes 0-15 emit tile0, lanes 16-31 emit tile1: ONE sigmoid + store
        const bool lo = lane < 16;
        const float o = SIG((lo ? z0 : z1) + nb2);
        if (lane < 32)
            out[((size_t)b * TLEN + t0 + (lo ? tt0 : tt1)) * NGF + f0 + jj] = o;
    }
#undef QUAD
#undef PAIR
}

extern "C" void kernel_launch(void* const* d_in, const int* in_sizes, int n_in,
                              void* d_out, int out_size, void* d_ws, size_t ws_size,
                              hipStream_t stream) {
    const float* x  = (const float*)d_in[0];
    const float* W1 = (const float*)d_in[1];
    const float* b1 = (const float*)d_in[2];
    const float* W2 = (const float*)d_in[3];
    const float* b2 = (const float*)d_in[4];
    float* out = (float*)d_out;

    const int B = in_sizes[0] / (NGF * TLEN);  // 32

    dim3 grid((TLEN / TC) * 5, B);             // (125, 32) = 4000 blocks
    relevance_mfma<<<grid, 256, 0, stream>>>(x, W1, b1, W2, b2, out);
}